// Round 5
// baseline (244.337 us; speedup 1.0000x reference)
//
#include <hip/hip_runtime.h>
#include <math.h>

#define Bn 8
#define Cn 64
#define Hn 128
#define Wn 128
#define HWn (Hn * Wn)

// weight fragment regions (shorts)
#define WOM_OFF 0
#define WDC_OFF 18432
#define WC_OFF 55296

typedef __attribute__((ext_vector_type(8))) short short8;
typedef __attribute__((ext_vector_type(4))) float floatx4;

__device__ __forceinline__ float bf2f(short s) {
  return __uint_as_float(((unsigned)(unsigned short)s) << 16);
}
__device__ __forceinline__ short f2bf(float f) {
  unsigned u = __float_as_uint(f);
  u += 0x7fff + ((u >> 16) & 1);  // RNE
  return (short)(u >> 16);
}

// ---------------------------------------------------------------------------
// Prep 1: weights -> bf16 MFMA-A-fragment order: one wave A-load is one
// contiguous 1KB coalesced read. frag[(cc*9+kk)*MT + mt][lane][8],
// lane holds row=mt*16+(lane&15), cin=cc*32+(lane>>4)*8+elem, tap kk.
// ---------------------------------------------------------------------------
__global__ __launch_bounds__(256) void k_prep_w(
    const float* __restrict__ w_om, const float* __restrict__ w_dc,
    const float* __restrict__ w_c, short* __restrict__ wt) {
  int idx = blockIdx.x * 256 + threadIdx.x;
  if (idx >= 92160) return;
  float v;
  if (idx < WDC_OFF) {  // om region, MT=2 (M=32)
    int e = idx;
    int elem = e & 7, lane = (e >> 3) & 63, mt = (e >> 9) & 1, t = e >> 10;
    int kk = t % 9, cc = t / 9;
    int row = mt * 16 + (lane & 15);
    int cin = cc * 32 + (lane >> 4) * 8 + elem;
    v = (row < 27) ? w_om[(row * 64 + cin) * 9 + kk] : 0.f;
  } else {  // dc / c regions, MT=4 (M=64)
    int e = (idx < WC_OFF) ? idx - WDC_OFF : idx - WC_OFF;
    const float* src = (idx < WC_OFF) ? w_dc : w_c;
    int elem = e & 7, lane = (e >> 3) & 63, mt = (e >> 9) & 3, t = e >> 11;
    int kk = t % 9, cc = t / 9;
    int row = mt * 16 + (lane & 15);
    int cin = cc * 32 + (lane >> 4) * 8 + elem;
    v = src[(row * 64 + cin) * 9 + kk];
  }
  wt[idx] = f2bf(v);
}

// ---------------------------------------------------------------------------
// Prep 2: x fp32 NCHW -> bf16 channels-last xT[b][h][w][64] (128B records).
// ---------------------------------------------------------------------------
__global__ __launch_bounds__(256) void k_prep_x(const float* __restrict__ x,
                                                short* __restrict__ xT) {
  __shared__ float tile[64][129];
  const int bid = blockIdx.x;
  const int b = bid & 7, h = bid >> 3;
  const int tid = threadIdx.x;
  const float* xb = x + (size_t)b * 64 * HWn + h * Wn;
  for (int i = tid; i < 8192; i += 256) {
    int c = i >> 7, w = i & 127;
    tile[c][w] = xb[c * HWn + w];
  }
  __syncthreads();
  short* dst = xT + ((size_t)(b * Hn + h) * Wn) * 64;
  for (int i = tid; i < 2048; i += 256) {
    int w = i >> 4, c4 = (i & 15) * 4;
    short4 o;
    o.x = f2bf(tile[c4 + 0][w]);
    o.y = f2bf(tile[c4 + 1][w]);
    o.z = f2bf(tile[c4 + 2][w]);
    o.w = f2bf(tile[c4 + 3][w]);
    *(short4*)(dst + (size_t)w * 64 + c4) = o;
  }
}

// ---------------------------------------------------------------------------
// Fused: conv_om -> som(LDS) -> bilinear params(LDS) -> deform conv ->
// bias+leakyReLU -> actT. Wave = 16 px x full M; B-fragments computed
// directly in registers (no val tile). 2 syncs total. LDS 16.4KB.
// ---------------------------------------------------------------------------
__global__ __launch_bounds__(256, 4) void k_omdef(
    const short* __restrict__ xT, const short* __restrict__ wt,
    const float* __restrict__ b_om, const float* __restrict__ b_dc,
    short* __restrict__ actT) {
  __shared__ float som[27 * 66];       // [cout][px], stride 66 (2-way free)
  __shared__ unsigned sbw[4 * 576];    // packed bilinear params
  unsigned* sb01 = sbw;
  unsigned* sb23 = sbw + 576;
  unsigned* sw01 = sbw + 1152;
  unsigned* sw23 = sbw + 1728;

  const int bid = blockIdx.x;
  const int b = bid & 7;
  const int r = bid >> 3;
  const int h = r >> 1, w0 = (r & 1) * 64;
  const int tid = threadIdx.x;
  const int wave = tid >> 6, lane = tid & 63, quad = lane >> 4, lr = lane & 15;
  const short* xb = xT + (size_t)b * HWn * 64;
  const int pxl = wave * 16 + lr;  // this lane's block-local pixel
  const int gxp = w0 + pxl;

  floatx4 zf = {0.f, 0.f, 0.f, 0.f};

  // ================= phase 1: conv_om (M=32) =================
  floatx4 aco[2] = {zf, zf};
  for (int kk = 0; kk < 9; ++kk) {
    int ky = kk / 3, kx = kk - ky * 3;
    int gy = h + ky - 1, gx = gxp + kx - 1;
    bool ok = ((unsigned)gy < (unsigned)Hn) && ((unsigned)gx < (unsigned)Wn);
    int gyc = min(max(gy, 0), Hn - 1), gxc = min(max(gx, 0), Wn - 1);
    const short* rec = xb + (size_t)(gyc * Wn + gxc) * 64 + quad * 8;
#pragma unroll
    for (int cc = 0; cc < 2; ++cc) {
      short8 bf = *(const short8*)(rec + cc * 32);
      if (!ok) bf = (short8){0, 0, 0, 0, 0, 0, 0, 0};
      const short* ap = wt + WOM_OFF + (size_t)((cc * 9 + kk) * 2) * 512 + lane * 8;
      short8 a0 = *(const short8*)(ap);
      short8 a1 = *(const short8*)(ap + 512);
      aco[0] = __builtin_amdgcn_mfma_f32_16x16x32_bf16(a0, bf, aco[0], 0, 0, 0);
      aco[1] = __builtin_amdgcn_mfma_f32_16x16x32_bf16(a1, bf, aco[1], 0, 0, 0);
    }
  }
  // om epilogue -> som
#pragma unroll
  for (int mt = 0; mt < 2; ++mt) {
#pragma unroll
    for (int rr = 0; rr < 4; ++rr) {
      int co = mt * 16 + quad * 4 + rr;
      if (co < 27) {
        float v = aco[mt][rr] + b_om[co];
        if (co >= 18) v = 2.f / (1.f + expf(-v));
        som[co * 66 + pxl] = v;
      }
    }
  }
  __syncthreads();

  // ================= phase A: bilinear params -> packed LDS =================
  for (int pr = tid; pr < 576; pr += 256) {
    int k = pr >> 6, p = pr & 63;
    float offy = som[(2 * k) * 66 + p];
    float offx = som[(2 * k + 1) * 66 + p];
    float m = som[(18 + k) * 66 + p];
    float py = (float)(h - 1 + (k / 3)) + offy;
    float px_ = (float)(w0 + p - 1 + (k % 3)) + offx;
    float fy = floorf(py), fx = floorf(px_);
    float ly = py - fy, lx = px_ - fx;
    int iy0 = (int)fy, ix0 = (int)fx;
    int iy1 = iy0 + 1, ix1 = ix0 + 1;
    bool vy0 = (iy0 >= 0) && (iy0 < Hn);
    bool vy1 = (iy1 >= 0) && (iy1 < Hn);
    bool vx0 = (ix0 >= 0) && (ix0 < Wn);
    bool vx1 = (ix1 >= 0) && (ix1 < Wn);
    unsigned cy0 = (unsigned)min(max(iy0, 0), Hn - 1);
    unsigned cy1 = (unsigned)min(max(iy1, 0), Hn - 1);
    unsigned cx0 = (unsigned)min(max(ix0, 0), Wn - 1);
    unsigned cx1 = (unsigned)min(max(ix1, 0), Wn - 1);
    sb01[pr] = (cy0 * Wn + cx0) | ((cy0 * Wn + cx1) << 16);
    sb23[pr] = (cy1 * Wn + cx0) | ((cy1 * Wn + cx1) << 16);
    float u0 = (vy0 && vx0) ? (1.f - ly) * (1.f - lx) * m : 0.f;
    float u1 = (vy0 && vx1) ? (1.f - ly) * lx * m : 0.f;
    float u2 = (vy1 && vx0) ? ly * (1.f - lx) * m : 0.f;
    float u3 = (vy1 && vx1) ? ly * lx * m : 0.f;
    sw01[pr] = (unsigned)(unsigned short)f2bf(u0) |
               ((unsigned)(unsigned short)f2bf(u1) << 16);
    sw23[pr] = (unsigned)(unsigned short)f2bf(u2) |
               ((unsigned)(unsigned short)f2bf(u3) << 16);
  }
  __syncthreads();

  // ================= phase 2: deformable conv (M=64) =================
  // Lane's B-fragment = chunk [quad*8..+8) of bilinear sample at (kk, pxl).
  floatx4 acc[4] = {zf, zf, zf, zf};
  for (int kk = 0; kk < 9; ++kk) {
    int pr = kk * 64 + pxl;
    unsigned a01 = sb01[pr], a23 = sb23[pr];   // broadcast across quads: free
    unsigned uw01 = sw01[pr], uw23 = sw23[pr];
    float u0 = bf2f((short)(uw01 & 0xFFFF));
    float u1 = bf2f((short)(uw01 >> 16));
    float u2 = bf2f((short)(uw23 & 0xFFFF));
    float u3 = bf2f((short)(uw23 >> 16));
    const short* s0 = xb + (size_t)(a01 & 0xFFFF) * 64 + quad * 8;
    const short* s1 = xb + (size_t)(a01 >> 16) * 64 + quad * 8;
    const short* s2 = xb + (size_t)(a23 & 0xFFFF) * 64 + quad * 8;
    const short* s3 = xb + (size_t)(a23 >> 16) * 64 + quad * 8;
#pragma unroll
    for (int cc = 0; cc < 2; ++cc) {
      short8 q0 = *(const short8*)(s0 + cc * 32);
      short8 q1 = *(const short8*)(s1 + cc * 32);
      short8 q2 = *(const short8*)(s2 + cc * 32);
      short8 q3 = *(const short8*)(s3 + cc * 32);
      short8 bf;
#pragma unroll
      for (int e = 0; e < 8; ++e) {
        float f = u0 * bf2f(q0[e]) + u1 * bf2f(q1[e]) + u2 * bf2f(q2[e]) +
                  u3 * bf2f(q3[e]);
        bf[e] = f2bf(f);
      }
      const short* ap = wt + WDC_OFF + (size_t)((cc * 9 + kk) * 4) * 512 + lane * 8;
#pragma unroll
      for (int mt = 0; mt < 4; ++mt) {
        short8 am = *(const short8*)(ap + mt * 512);
        acc[mt] = __builtin_amdgcn_mfma_f32_16x16x32_bf16(am, bf, acc[mt], 0, 0, 0);
      }
    }
  }

  // epilogue: bias + leaky ReLU -> actT[b][h][w][64]
  short* ab = actT + ((size_t)(b * Hn + h) * Wn + w0) * 64;
#pragma unroll
  for (int mt = 0; mt < 4; ++mt) {
    int c0 = mt * 16 + quad * 4;
    short4 o;
    float v;
    v = acc[mt][0] + b_dc[c0 + 0]; o.x = f2bf(v > 0.f ? v : 0.2f * v);
    v = acc[mt][1] + b_dc[c0 + 1]; o.y = f2bf(v > 0.f ? v : 0.2f * v);
    v = acc[mt][2] + b_dc[c0 + 2]; o.z = f2bf(v > 0.f ? v : 0.2f * v);
    v = acc[mt][3] + b_dc[c0 + 3]; o.w = f2bf(v > 0.f ? v : 0.2f * v);
    *(short4*)(ab + (size_t)pxl * 64 + c0) = o;
  }
}

// ---------------------------------------------------------------------------
// conv_out: no LDS, no syncs. Wave = 16 px x full M=64; B-fragments are
// direct shifted reads from actT (clamp+zero). Epilogue: bias + residual.
// ---------------------------------------------------------------------------
__global__ __launch_bounds__(256, 4) void k_conv_out(
    const short* __restrict__ actT, const short* __restrict__ wt,
    const float* __restrict__ b_c, const float* __restrict__ x,
    float* __restrict__ out) {
  const int bid = blockIdx.x;
  const int b = bid & 7;
  const int r = bid >> 3;
  const int h = r >> 1, w0 = (r & 1) * 64;
  const int tid = threadIdx.x;
  const int wave = tid >> 6, lane = tid & 63, quad = lane >> 4, lr = lane & 15;
  const short* ab = actT + (size_t)b * HWn * 64;
  const int pxl = wave * 16 + lr;
  const int gxp = w0 + pxl;

  floatx4 zf = {0.f, 0.f, 0.f, 0.f};
  floatx4 acc[4] = {zf, zf, zf, zf};
  for (int kk = 0; kk < 9; ++kk) {
    int ky = kk / 3, kx = kk - ky * 3;
    int gy = h + ky - 1, gx = gxp + kx - 1;
    bool ok = ((unsigned)gy < (unsigned)Hn) && ((unsigned)gx < (unsigned)Wn);
    int gyc = min(max(gy, 0), Hn - 1), gxc = min(max(gx, 0), Wn - 1);
    const short* rec = ab + (size_t)(gyc * Wn + gxc) * 64 + quad * 8;
#pragma unroll
    for (int cc = 0; cc < 2; ++cc) {
      short8 bf = *(const short8*)(rec + cc * 32);
      if (!ok) bf = (short8){0, 0, 0, 0, 0, 0, 0, 0};
      const short* ap = wt + WC_OFF + (size_t)((cc * 9 + kk) * 4) * 512 + lane * 8;
#pragma unroll
      for (int mt = 0; mt < 4; ++mt) {
        short8 am = *(const short8*)(ap + mt * 512);
        acc[mt] = __builtin_amdgcn_mfma_f32_16x16x32_bf16(am, bf, acc[mt], 0, 0, 0);
      }
    }
  }

#pragma unroll
  for (int mt = 0; mt < 4; ++mt) {
#pragma unroll
    for (int rr = 0; rr < 4; ++rr) {
      int cout = mt * 16 + quad * 4 + rr;
      size_t gidx = ((size_t)(b * 64 + cout) * Hn + h) * Wn + w0 + pxl;
      out[gidx] = acc[mt][rr] + b_c[cout] + x[gidx];
    }
  }
}

// ---------------------------------------------------------------------------
extern "C" void kernel_launch(void* const* d_in, const int* in_sizes, int n_in,
                              void* d_out, int out_size, void* d_ws,
                              size_t ws_size, hipStream_t stream) {
  const float* x = (const float*)d_in[0];
  const float* w_om = (const float*)d_in[1];
  const float* b_om = (const float*)d_in[2];
  const float* w_dc = (const float*)d_in[3];
  const float* b_dc = (const float*)d_in[4];
  const float* w_c = (const float*)d_in[5];
  const float* b_c = (const float*)d_in[6];
  float* out = (float*)d_out;

  // ws: xT bf16 (16.8 MB) | actT bf16 (16.8 MB) | weight frags (184 KB)
  short* xT = (short*)d_ws;
  short* actT = xT + (size_t)Bn * HWn * 64;
  short* wt = actT + (size_t)Bn * HWn * 64;

  k_prep_w<<<dim3(360), 256, 0, stream>>>(w_om, w_dc, w_c, wt);
  k_prep_x<<<dim3(1024), 256, 0, stream>>>(x, xT);
  k_omdef<<<dim3(2048), 256, 0, stream>>>(xT, wt, b_om, b_dc, actT);
  k_conv_out<<<dim3(2048), 256, 0, stream>>>(actT, wt, b_c, x, out);
}

// Round 6
// 231.050 us; speedup vs baseline: 1.0575x; 1.0575x over previous
//
#include <hip/hip_runtime.h>
#include <math.h>

#define Bn 8
#define Cn 64
#define Hn 128
#define Wn 128
#define HWn (Hn * Wn)

// weight fragment regions (shorts)
#define WOM_OFF 0
#define WDC_OFF 18432
#define WC_OFF 55296

typedef __attribute__((ext_vector_type(8))) short short8;
typedef __attribute__((ext_vector_type(4))) float floatx4;

__device__ __forceinline__ float bf2f(short s) {
  return __uint_as_float(((unsigned)(unsigned short)s) << 16);
}
__device__ __forceinline__ short f2bf(float f) {
  unsigned u = __float_as_uint(f);
  u += 0x7fff + ((u >> 16) & 1);  // RNE
  return (short)(u >> 16);
}

// ---------------------------------------------------------------------------
// Prep 1: weights -> bf16 MFMA-A-fragment order: one wave A-load is one
// contiguous 1KB read. frag[(cc*9+kk)*MT + mt][lane][8],
// lane holds row=mt*16+(lane&15), cin=cc*32+(lane>>4)*8+elem, tap kk.
// ---------------------------------------------------------------------------
__global__ __launch_bounds__(256) void k_prep_w(
    const float* __restrict__ w_om, const float* __restrict__ w_dc,
    const float* __restrict__ w_c, short* __restrict__ wt) {
  int idx = blockIdx.x * 256 + threadIdx.x;
  if (idx >= 92160) return;
  float v;
  if (idx < WDC_OFF) {  // om region, MT=2 (M=32)
    int e = idx;
    int elem = e & 7, lane = (e >> 3) & 63, mt = (e >> 9) & 1, t = e >> 10;
    int kk = t % 9, cc = t / 9;
    int row = mt * 16 + (lane & 15);
    int cin = cc * 32 + (lane >> 4) * 8 + elem;
    v = (row < 27) ? w_om[(row * 64 + cin) * 9 + kk] : 0.f;
  } else {  // dc / c regions, MT=4 (M=64)
    int e = (idx < WC_OFF) ? idx - WDC_OFF : idx - WC_OFF;
    const float* src = (idx < WC_OFF) ? w_dc : w_c;
    int elem = e & 7, lane = (e >> 3) & 63, mt = (e >> 9) & 3, t = e >> 11;
    int kk = t % 9, cc = t / 9;
    int row = mt * 16 + (lane & 15);
    int cin = cc * 32 + (lane >> 4) * 8 + elem;
    v = src[(row * 64 + cin) * 9 + kk];
  }
  wt[idx] = f2bf(v);
}

// ---------------------------------------------------------------------------
// Prep 2: x fp32 NCHW -> bf16 channels-last xT[b][h][w][64] (128B records).
// ---------------------------------------------------------------------------
__global__ __launch_bounds__(256) void k_prep_x(const float* __restrict__ x,
                                                short* __restrict__ xT) {
  __shared__ float tile[64][129];
  const int bid = blockIdx.x;
  const int b = bid & 7, h = bid >> 3;
  const int tid = threadIdx.x;
  const float* xb = x + (size_t)b * 64 * HWn + h * Wn;
  for (int i = tid; i < 8192; i += 256) {
    int c = i >> 7, w = i & 127;
    tile[c][w] = xb[c * HWn + w];
  }
  __syncthreads();
  short* dst = xT + ((size_t)(b * Hn + h) * Wn) * 64;
  for (int i = tid; i < 2048; i += 256) {
    int w = i >> 4, c4 = (i & 15) * 4;
    short4 o;
    o.x = f2bf(tile[c4 + 0][w]);
    o.y = f2bf(tile[c4 + 1][w]);
    o.z = f2bf(tile[c4 + 2][w]);
    o.w = f2bf(tile[c4 + 3][w]);
    *(short4*)(dst + (size_t)w * 64 + c4) = o;
  }
}

// ---------------------------------------------------------------------------
// Fused: conv_om -> som(LDS) -> bilinear params(LDS) -> deform conv ->
// bias+leakyReLU -> actT. A-fragments staged in LDS (om: whole 36KB; dc:
// per-cc 36KB) so global VMEM serves only pixel gathers.
// LDS 53.2KB -> 3 blocks/CU.
// ---------------------------------------------------------------------------
__global__ __launch_bounds__(256, 3) void k_omdef(
    const short* __restrict__ xT, const short* __restrict__ wt,
    const float* __restrict__ b_om, const float* __restrict__ b_dc,
    short* __restrict__ actT) {
  __shared__ __attribute__((aligned(16))) short lw[18432];  // 36KB A-stage
  __shared__ float som[27 * 66];                            // 7.1KB
  __shared__ unsigned sbw[4 * 576];                         // 9.2KB params
  unsigned* sb01 = sbw;
  unsigned* sb23 = sbw + 576;
  unsigned* sw01 = sbw + 1152;
  unsigned* sw23 = sbw + 1728;

  const int bid = blockIdx.x;
  const int b = bid & 7;
  const int r = bid >> 3;
  const int h = r >> 1, w0 = (r & 1) * 64;
  const int tid = threadIdx.x;
  const int wave = tid >> 6, lane = tid & 63, quad = lane >> 4, lr = lane & 15;
  const short* xb = xT + (size_t)b * HWn * 64;
  const int pxl = wave * 16 + lr;  // this lane's block-local pixel
  const int gxp = w0 + pxl;

  floatx4 zf = {0.f, 0.f, 0.f, 0.f};

  // ---- stage om A-fragments (both cc halves, 36KB) ----
  {
    const short8* src = (const short8*)(wt + WOM_OFF);
    short8* dst = (short8*)lw;
    for (int i = tid; i < 2304; i += 256) dst[i] = src[i];
  }
  __syncthreads();

  // ================= phase 1: conv_om (M=32) =================
  floatx4 aco[2] = {zf, zf};
#pragma unroll 3
  for (int kk = 0; kk < 9; ++kk) {
    int ky = kk / 3, kx = kk - ky * 3;
    int gy = h + ky - 1, gx = gxp + kx - 1;
    bool ok = ((unsigned)gy < (unsigned)Hn) && ((unsigned)gx < (unsigned)Wn);
    int gyc = min(max(gy, 0), Hn - 1), gxc = min(max(gx, 0), Wn - 1);
    const short* rec = xb + (size_t)(gyc * Wn + gxc) * 64 + quad * 8;
#pragma unroll
    for (int cc = 0; cc < 2; ++cc) {
      short8 bf = *(const short8*)(rec + cc * 32);
      if (!ok) bf = (short8){0, 0, 0, 0, 0, 0, 0, 0};
      short8 a0 = *(const short8*)&lw[((cc * 9 + kk) * 2 + 0) * 512 + lane * 8];
      short8 a1 = *(const short8*)&lw[((cc * 9 + kk) * 2 + 1) * 512 + lane * 8];
      aco[0] = __builtin_amdgcn_mfma_f32_16x16x32_bf16(a0, bf, aco[0], 0, 0, 0);
      aco[1] = __builtin_amdgcn_mfma_f32_16x16x32_bf16(a1, bf, aco[1], 0, 0, 0);
    }
  }
  // om epilogue -> som
#pragma unroll
  for (int mt = 0; mt < 2; ++mt) {
#pragma unroll
    for (int rr = 0; rr < 4; ++rr) {
      int co = mt * 16 + quad * 4 + rr;
      if (co < 27) {
        float v = aco[mt][rr] + b_om[co];
        if (co >= 18) v = 2.f / (1.f + expf(-v));
        som[co * 66 + pxl] = v;
      }
    }
  }
  __syncthreads();  // som ready; phase1 lw reads done

  // ---- stage dc cc0 A-fragments (overlaps phase A latency) ----
  {
    const short8* src = (const short8*)(wt + WDC_OFF);
    short8* dst = (short8*)lw;
    for (int i = tid; i < 2304; i += 256) dst[i] = src[i];
  }
  // ---- phase A: bilinear params -> packed LDS ----
  for (int pr = tid; pr < 576; pr += 256) {
    int k = pr >> 6, p = pr & 63;
    float offy = som[(2 * k) * 66 + p];
    float offx = som[(2 * k + 1) * 66 + p];
    float m = som[(18 + k) * 66 + p];
    float py = (float)(h - 1 + (k / 3)) + offy;
    float px_ = (float)(w0 + p - 1 + (k % 3)) + offx;
    float fy = floorf(py), fx = floorf(px_);
    float ly = py - fy, lx = px_ - fx;
    int iy0 = (int)fy, ix0 = (int)fx;
    int iy1 = iy0 + 1, ix1 = ix0 + 1;
    bool vy0 = (iy0 >= 0) && (iy0 < Hn);
    bool vy1 = (iy1 >= 0) && (iy1 < Hn);
    bool vx0 = (ix0 >= 0) && (ix0 < Wn);
    bool vx1 = (ix1 >= 0) && (ix1 < Wn);
    unsigned cy0 = (unsigned)min(max(iy0, 0), Hn - 1);
    unsigned cy1 = (unsigned)min(max(iy1, 0), Hn - 1);
    unsigned cx0 = (unsigned)min(max(ix0, 0), Wn - 1);
    unsigned cx1 = (unsigned)min(max(ix1, 0), Wn - 1);
    sb01[pr] = (cy0 * Wn + cx0) | ((cy0 * Wn + cx1) << 16);
    sb23[pr] = (cy1 * Wn + cx0) | ((cy1 * Wn + cx1) << 16);
    float u0 = (vy0 && vx0) ? (1.f - ly) * (1.f - lx) * m : 0.f;
    float u1 = (vy0 && vx1) ? (1.f - ly) * lx * m : 0.f;
    float u2 = (vy1 && vx0) ? ly * (1.f - lx) * m : 0.f;
    float u3 = (vy1 && vx1) ? ly * lx * m : 0.f;
    sw01[pr] = (unsigned)(unsigned short)f2bf(u0) |
               ((unsigned)(unsigned short)f2bf(u1) << 16);
    sw23[pr] = (unsigned)(unsigned short)f2bf(u2) |
               ((unsigned)(unsigned short)f2bf(u3) << 16);
  }
  __syncthreads();  // params + staged cc0 ready

  // ================= phase 2: deformable conv (M=64) =================
  floatx4 acc[4] = {zf, zf, zf, zf};
  for (int cc = 0; cc < 2; ++cc) {
    if (cc) {
      __syncthreads();  // cc0 A-reads done
      const short8* src = (const short8*)(wt + WDC_OFF + 18432);
      short8* dst = (short8*)lw;
      for (int i = tid; i < 2304; i += 256) dst[i] = src[i];
      __syncthreads();
    }
#pragma unroll 3
    for (int kk = 0; kk < 9; ++kk) {
      int pr = kk * 64 + pxl;
      unsigned a01 = sb01[pr], a23 = sb23[pr];
      unsigned uw01 = sw01[pr], uw23 = sw23[pr];
      float u0 = bf2f((short)(uw01 & 0xFFFF));
      float u1 = bf2f((short)(uw01 >> 16));
      float u2 = bf2f((short)(uw23 & 0xFFFF));
      float u3 = bf2f((short)(uw23 >> 16));
      int co = cc * 32 + quad * 8;
      short8 q0 = *(const short8*)(xb + (size_t)(a01 & 0xFFFF) * 64 + co);
      short8 q1 = *(const short8*)(xb + (size_t)(a01 >> 16) * 64 + co);
      short8 q2 = *(const short8*)(xb + (size_t)(a23 & 0xFFFF) * 64 + co);
      short8 q3 = *(const short8*)(xb + (size_t)(a23 >> 16) * 64 + co);
      short8 bf;
#pragma unroll
      for (int e = 0; e < 8; ++e) {
        float f = u0 * bf2f(q0[e]) + u1 * bf2f(q1[e]) + u2 * bf2f(q2[e]) +
                  u3 * bf2f(q3[e]);
        bf[e] = f2bf(f);
      }
#pragma unroll
      for (int mt = 0; mt < 4; ++mt) {
        short8 am = *(const short8*)&lw[(kk * 4 + mt) * 512 + lane * 8];
        acc[mt] = __builtin_amdgcn_mfma_f32_16x16x32_bf16(am, bf, acc[mt], 0, 0, 0);
      }
    }
  }

  // epilogue: bias + leaky ReLU -> actT[b][h][w][64]
  short* ab = actT + ((size_t)(b * Hn + h) * Wn + w0) * 64;
#pragma unroll
  for (int mt = 0; mt < 4; ++mt) {
    int c0 = mt * 16 + quad * 4;
    short4 o;
    float v;
    v = acc[mt][0] + b_dc[c0 + 0]; o.x = f2bf(v > 0.f ? v : 0.2f * v);
    v = acc[mt][1] + b_dc[c0 + 1]; o.y = f2bf(v > 0.f ? v : 0.2f * v);
    v = acc[mt][2] + b_dc[c0 + 2]; o.z = f2bf(v > 0.f ? v : 0.2f * v);
    v = acc[mt][3] + b_dc[c0 + 3]; o.w = f2bf(v > 0.f ? v : 0.2f * v);
    *(short4*)(ab + (size_t)pxl * 64 + c0) = o;
  }
}

// ---------------------------------------------------------------------------
// conv_out: A staged per-cc in LDS; B = direct shifted reads from actT;
// epilogue via LDS fp32 transpose -> coalesced float4 out stores + residual.
// LDS 36.9KB -> 4 blocks/CU.
// ---------------------------------------------------------------------------
__global__ __launch_bounds__(256, 4) void k_conv_out(
    const short* __restrict__ actT, const short* __restrict__ wt,
    const float* __restrict__ b_c, const float* __restrict__ x,
    float* __restrict__ out) {
  __shared__ __attribute__((aligned(16))) short lw[18432];  // 36KB

  const int bid = blockIdx.x;
  const int b = bid & 7;
  const int r = bid >> 3;
  const int h = r >> 1, w0 = (r & 1) * 64;
  const int tid = threadIdx.x;
  const int wave = tid >> 6, lane = tid & 63, quad = lane >> 4, lr = lane & 15;
  const short* ab = actT + (size_t)b * HWn * 64;
  const int pxl = wave * 16 + lr;
  const int gxp = w0 + pxl;

  floatx4 zf = {0.f, 0.f, 0.f, 0.f};
  floatx4 acc[4] = {zf, zf, zf, zf};

  for (int cc = 0; cc < 2; ++cc) {
    if (cc) __syncthreads();  // previous A-reads done
    {
      const short8* src = (const short8*)(wt + WC_OFF + cc * 18432);
      short8* dst = (short8*)lw;
      for (int i = tid; i < 2304; i += 256) dst[i] = src[i];
    }
    __syncthreads();
#pragma unroll 3
    for (int kk = 0; kk < 9; ++kk) {
      int ky = kk / 3, kx = kk - ky * 3;
      int gy = h + ky - 1, gx = gxp + kx - 1;
      bool ok = ((unsigned)gy < (unsigned)Hn) && ((unsigned)gx < (unsigned)Wn);
      int gyc = min(max(gy, 0), Hn - 1), gxc = min(max(gx, 0), Wn - 1);
      short8 bf = *(const short8*)(ab + (size_t)(gyc * Wn + gxc) * 64 +
                                   cc * 32 + quad * 8);
      if (!ok) bf = (short8){0, 0, 0, 0, 0, 0, 0, 0};
#pragma unroll
      for (int mt = 0; mt < 4; ++mt) {
        short8 am = *(const short8*)&lw[(kk * 4 + mt) * 512 + lane * 8];
        acc[mt] = __builtin_amdgcn_mfma_f32_16x16x32_bf16(am, bf, acc[mt], 0, 0, 0);
      }
    }
  }
  __syncthreads();  // all A-reads done; reuse lw as fp32 tile

  // transpose acc -> ot[cout][px] (stride 66)
  float* ot = (float*)lw;
#pragma unroll
  for (int mt = 0; mt < 4; ++mt) {
#pragma unroll
    for (int rr = 0; rr < 4; ++rr) {
      ot[(mt * 16 + quad * 4 + rr) * 66 + pxl] = acc[mt][rr];
    }
  }
  __syncthreads();

  // coalesced epilogue: thread = (cout row, 16-px segment)
  const int row = tid >> 2, seg = tid & 3;
  const float bias = b_c[row];
  const size_t gbase = ((size_t)(b * 64 + row) * Hn + h) * Wn + w0 + seg * 16;
  const float* xr = x + gbase;
  float* op = out + gbase;
#pragma unroll
  for (int j = 0; j < 4; ++j) {
    floatx4 t = *(const floatx4*)&ot[row * 66 + seg * 16 + j * 4];
    floatx4 xv = *(const floatx4*)&xr[j * 4];
    t = t + xv;
    t[0] += bias; t[1] += bias; t[2] += bias; t[3] += bias;
    *(floatx4*)&op[j * 4] = t;
  }
}

// ---------------------------------------------------------------------------
extern "C" void kernel_launch(void* const* d_in, const int* in_sizes, int n_in,
                              void* d_out, int out_size, void* d_ws,
                              size_t ws_size, hipStream_t stream) {
  const float* x = (const float*)d_in[0];
  const float* w_om = (const float*)d_in[1];
  const float* b_om = (const float*)d_in[2];
  const float* w_dc = (const float*)d_in[3];
  const float* b_dc = (const float*)d_in[4];
  const float* w_c = (const float*)d_in[5];
  const float* b_c = (const float*)d_in[6];
  float* out = (float*)d_out;

  // ws: xT bf16 (16.8 MB) | actT bf16 (16.8 MB) | weight frags (184 KB)
  short* xT = (short*)d_ws;
  short* actT = xT + (size_t)Bn * HWn * 64;
  short* wt = actT + (size_t)Bn * HWn * 64;

  k_prep_w<<<dim3(360), 256, 0, stream>>>(w_om, w_dc, w_c, wt);
  k_prep_x<<<dim3(1024), 256, 0, stream>>>(x, xT);
  k_omdef<<<dim3(2048), 256, 0, stream>>>(xT, wt, b_om, b_dc, actT);
  k_conv_out<<<dim3(2048), 256, 0, stream>>>(actT, wt, b_c, x, out);
}